// Round 1
// baseline (290.276 us; speedup 1.0000x reference)
//
#include <hip/hip_runtime.h>
#include <cstddef>

typedef unsigned short u16;
typedef unsigned int u32;
typedef __attribute__((ext_vector_type(8))) __bf16 bf16x8;
typedef __attribute__((ext_vector_type(4))) float f32x4;

constexpr int kB = 8, kC = 256, kCI = 128, kN = 4096, kM = 1024;
constexpr int kSPLIT = 2, kMCH = kM / kSPLIT, kNCH = kMCH / 64;
constexpr float kEPS = 1e-5f;
constexpr float kLOG2E = 1.44269504088896f;

__device__ __forceinline__ u16 f2bf(float f) {
    u32 u = __float_as_uint(f);
    u32 r = (u + 0x7fffu + ((u >> 16) & 1u)) >> 16;
    return (u16)r;
}

// ---------------------------------------------------------------------------
// prep: weights -> bf16; fold BN scale into Ww; bb = (bw-mean)*sc+beta
// Wth/bth additionally scaled by log2(e) so softmax runs in exp2 domain.
// ---------------------------------------------------------------------------
__global__ __launch_bounds__(256) void prep_kernel(const float* __restrict__ Wth,
                                                   const float* __restrict__ bth,
                                                   const float* __restrict__ Wph,
                                                   const float* __restrict__ Wg,
                                                   const float* __restrict__ Ww,
                                                   const float* __restrict__ bw,
                                                   const float* __restrict__ gamma,
                                                   const float* __restrict__ beta,
                                                   const float* __restrict__ mean,
                                                   const float* __restrict__ var,
                                                   u16* __restrict__ Wthb,
                                                   u16* __restrict__ Wphb,
                                                   u16* __restrict__ Wgb,
                                                   u16* __restrict__ Wwsb,
                                                   float* __restrict__ bb,
                                                   float* __restrict__ bthl) {
    int idx = blockIdx.x * 256 + threadIdx.x;
    if (idx < 32768) {
        Wthb[idx] = f2bf(Wth[idx] * kLOG2E);
        if (idx < kCI) bthl[idx] = bth[idx] * kLOG2E;
    } else if (idx < 65536) {
        int j = idx - 32768; Wphb[j] = f2bf(Wph[j]);
    } else if (idx < 98304) {
        int j = idx - 65536; Wgb[j] = f2bf(Wg[j]);
    } else {
        int j = idx - 98304;
        int co = j >> 7;
        float sc = gamma[co] * rsqrtf(var[co] + kEPS);
        Wwsb[j] = f2bf(Ww[j] * sc);
        if ((j & 127) == 0) bb[co] = (bw[co] - mean[co]) * sc + beta[co];
    }
}

// ---------------------------------------------------------------------------
// MFMA producer conv1x1 body (optionally fused 2x2 avg-pool on input).
// ---------------------------------------------------------------------------
template <int POOL>
__device__ __forceinline__ void conv_body(const float* __restrict__ x,
                                          const u16* __restrict__ Wb,
                                          const float* __restrict__ bias,
                                          u16* __restrict__ out, int Mn,
                                          int cmajor, int b, int n0) {
    __shared__ __align__(16) u16 w_lds[128 * 72];   // [ci][c] stride 72 (16B-offset rows)
    __shared__ __align__(16) u16 x_lds[64 * 64];    // [n][c] swizzled
    int t = threadIdx.x;
    int w = t >> 6, lane = t & 63, l15 = lane & 15, quad = lane >> 4;
    int xn = t & 63, cbb = (t >> 6) * 2;

    f32x4 acc[8];
#pragma unroll
    for (int i = 0; i < 8; i++) acc[i] = (f32x4){0.f, 0.f, 0.f, 0.f};

    for (int c0 = 0; c0 < kC; c0 += 64) {
        __syncthreads();
#pragma unroll
        for (int i = 0; i < 4; i++) {
            int u = t + 256 * i;
            int ci = u >> 3, blk = u & 7;
            *(uint4*)&w_lds[ci * 72 + blk * 8] =
                *(const uint4*)&Wb[ci * kC + c0 + blk * 8];
        }
#pragma unroll
        for (int cc = 0; cc < 2; cc++) {
            int cb = cbb + cc;
            float f[8];
            if (POOL) {
                int p = n0 + xn, ph_ = p >> 5, pw_ = p & 31;
#pragma unroll
                for (int j = 0; j < 8; j++) {
                    const float* src = x + ((size_t)(b * kC + c0 + cb * 8 + j) * 64
                                            + 2 * ph_) * 64 + 2 * pw_;
                    float2 a = *(const float2*)src;
                    float2 b2 = *(const float2*)(src + 64);
                    f[j] = 0.25f * (a.x + a.y + b2.x + b2.y);
                }
            } else {
#pragma unroll
                for (int j = 0; j < 8; j++)
                    f[j] = x[(size_t)(b * kC + c0 + cb * 8 + j) * Mn + n0 + xn];
            }
            uint4 pk;
            pk.x = (u32)f2bf(f[0]) | ((u32)f2bf(f[1]) << 16);
            pk.y = (u32)f2bf(f[2]) | ((u32)f2bf(f[3]) << 16);
            pk.z = (u32)f2bf(f[4]) | ((u32)f2bf(f[5]) << 16);
            pk.w = (u32)f2bf(f[6]) | ((u32)f2bf(f[7]) << 16);
            *(uint4*)&x_lds[xn * 64 + ((cb ^ (xn & 7)) * 8)] = pk;
        }
        __syncthreads();

#pragma unroll
        for (int ks = 0; ks < 2; ks++) {
            int px = w * 16 + l15;
            bf16x8 xf = *(const bf16x8*)&x_lds[px * 64 + (((ks * 4 + quad) ^ (px & 7)) * 8)];
#pragma unroll
            for (int ct = 0; ct < 8; ct++) {
                bf16x8 wf = *(const bf16x8*)&w_lds[(ct * 16 + l15) * 72 + ks * 32 + quad * 8];
                if (cmajor)
                    acc[ct] = __builtin_amdgcn_mfma_f32_16x16x32_bf16(xf, wf, acc[ct], 0, 0, 0);
                else
                    acc[ct] = __builtin_amdgcn_mfma_f32_16x16x32_bf16(wf, xf, acc[ct], 0, 0, 0);
            }
        }
    }

    if (cmajor == 0) {
        int px = n0 + w * 16 + l15;
#pragma unroll
        for (int ct = 0; ct < 8; ct++) {
            int ci0 = ct * 16 + quad * 4;
            uint2 pk;
            pk.x = (u32)f2bf(acc[ct][0] + bias[ci0 + 0]) |
                   ((u32)f2bf(acc[ct][1] + bias[ci0 + 1]) << 16);
            pk.y = (u32)f2bf(acc[ct][2] + bias[ci0 + 2]) |
                   ((u32)f2bf(acc[ct][3] + bias[ci0 + 3]) << 16);
            *(uint2*)&out[(size_t)(b * Mn + px) * kCI + ci0] = pk;
        }
    } else {
        int px = n0 + w * 16 + quad * 4;
#pragma unroll
        for (int ct = 0; ct < 8; ct++) {
            int ci = ct * 16 + l15;
            float bs = bias[ci];
            uint2 pk;
            pk.x = (u32)f2bf(acc[ct][0] + bs) | ((u32)f2bf(acc[ct][1] + bs) << 16);
            pk.y = (u32)f2bf(acc[ct][2] + bs) | ((u32)f2bf(acc[ct][3] + bs) << 16);
            *(uint2*)&out[(size_t)(b * kCI + ci) * Mn + px] = pk;
        }
    }
}

// theta conv: no pool, n-major out (log2e-scaled weights/bias)
__global__ __launch_bounds__(256) void convth_kernel(const float* __restrict__ x,
                                                     const u16* __restrict__ Wb,
                                                     const float* __restrict__ bias,
                                                     u16* __restrict__ out) {
    conv_body<0>(x, Wb, bias, out, kN, 0, blockIdx.y, blockIdx.x * 64);
}

// fused phi (z=0, n-major) + g (z=1, ci-major) convs with pooled input
__global__ __launch_bounds__(256) void convpg_kernel(const float* __restrict__ q,
                                                     const float* __restrict__ v,
                                                     const u16* __restrict__ Wph,
                                                     const u16* __restrict__ Wg,
                                                     const float* __restrict__ bph,
                                                     const float* __restrict__ bg,
                                                     u16* __restrict__ phi,
                                                     u16* __restrict__ g) {
    int z = blockIdx.z;
    conv_body<1>(z ? v : q, z ? Wg : Wph, z ? bg : bph, z ? g : phi,
                 kM, z, blockIdx.y, blockIdx.x * 64);
}

// ---------------------------------------------------------------------------
// Split-m flash attention (SPLIT=2), bf16 MFMA, exp2-domain online softmax.
// Each block: 64 n x 512 m, 8 chunks. phi double-buffered in LDS (reg
// prefetch, 1 barrier/chunk); g fragments loaded DIRECTLY from global
// (layout [ci][m] makes MFMA A-frags contiguous 16B); P via per-wave LDS.
// Outputs unnormalized O' (f32) + per-row (m,l); combine fused into final.
// ---------------------------------------------------------------------------
__global__ __launch_bounds__(256, 4) void attn_kernel(const u16* __restrict__ theta,
                                                      const u16* __restrict__ phi,
                                                      const u16* __restrict__ g,
                                                      float* __restrict__ Opart,
                                                      float* __restrict__ ml) {
    __shared__ __align__(16) u16 ph_lds[16384];  // 2 x [ks:4][m:64][kblk^sw][8]  32KB
    __shared__ __align__(16) u16 p_lds[4096];    // [wave:4][frag:2][col:16][k:32] 8KB

    int t = threadIdx.x, b = blockIdx.y, n0 = blockIdx.x * 64, sp = blockIdx.z;
    int w = t >> 6, lane = t & 63, l15 = lane & 15, quad = lane >> 4;
    int sw = (l15 >> 1) & 3;

    // theta B-frags in registers for the whole kernel (16 n per wave)
    bf16x8 thf[4];
    const u16* thB = theta + ((size_t)(b * kN) + n0 + w * 16 + l15) * kCI;
#pragma unroll
    for (int ks = 0; ks < 4; ks++)
        thf[ks] = *(const bf16x8*)&thB[ks * 32 + quad * 8];

    f32x4 oacc[8];
#pragma unroll
    for (int ct = 0; ct < 8; ct++) oacc[ct] = (f32x4){0.f, 0.f, 0.f, 0.f};
    float m_ = -1e30f, l_ = 0.f;

    const u16* phB = phi + ((size_t)b * kM + sp * kMCH) * kCI;
    const u16* gB  = g + (size_t)b * kCI * kM + sp * kMCH;
    u16* pw = p_lds + w * 1024;

    // staging map (per thread, iter i): u = t + 256*i; row=u>>4; cb=u&15
    int ldo_[4], go_[4];
#pragma unroll
    for (int i = 0; i < 4; i++) {
        int u = t + 256 * i, row = u >> 4, cb = u & 15;
        ldo_[i] = (cb >> 2) * 2048 + row * 32 + (((cb & 3) ^ ((row >> 1) & 3)) * 8);
        go_[i] = row * kCI + cb * 8;
    }

    uint4 preg[4];
#pragma unroll
    for (int i = 0; i < 4; i++) preg[i] = *(const uint4*)&phB[go_[i]];

    for (int ch = 0; ch < kNCH; ch++) {
        u16* buf = ph_lds + (ch & 1) * 8192;
#pragma unroll
        for (int i = 0; i < 4; i++) *(uint4*)&buf[ldo_[i]] = preg[i];
        __syncthreads();
        if (ch + 1 < kNCH) {
            const u16* nsrc = phB + (ch + 1) * 64 * kCI;
#pragma unroll
            for (int i = 0; i < 4; i++) preg[i] = *(const uint4*)&nsrc[go_[i]];
        }

        // S' = phi(64m x 128k) . theta^T : 4 mt-tiles, C-col = n (log2 domain)
        f32x4 sacc[4];
#pragma unroll
        for (int mt = 0; mt < 4; mt++) sacc[mt] = (f32x4){0.f, 0.f, 0.f, 0.f};
#pragma unroll
        for (int ks = 0; ks < 4; ks++)
#pragma unroll
            for (int mt = 0; mt < 4; mt++) {
                bf16x8 a = *(const bf16x8*)&buf[ks * 2048 + (mt * 16 + l15) * 32 +
                                                ((quad ^ sw) * 8)];
                sacc[mt] = __builtin_amdgcn_mfma_f32_16x16x32_bf16(a, thf[ks], sacc[mt], 0, 0, 0);
            }

        // online softmax (exp2 domain) with defer-max threshold 8
        float mc = -1e30f;
#pragma unroll
        for (int mt = 0; mt < 4; mt++)
#pragma unroll
            for (int r = 0; r < 4; r++) mc = fmaxf(mc, sacc[mt][r]);
        mc = fmaxf(mc, __shfl_xor(mc, 16, 64));
        mc = fmaxf(mc, __shfl_xor(mc, 32, 64));
        if (__any(mc > m_ + 8.0f)) {
            float mn = fmaxf(m_, mc);
            float al = exp2f(m_ - mn);
            m_ = mn;
            l_ *= al;
#pragma unroll
            for (int ct = 0; ct < 8; ct++)
#pragma unroll
                for (int r = 0; r < 4; r++) oacc[ct][r] *= al;
        }
        float rs = 0.f;
#pragma unroll
        for (int mt = 0; mt < 4; mt++)
#pragma unroll
            for (int r = 0; r < 4; r++) {
                float p = exp2f(sacc[mt][r] - m_);
                sacc[mt][r] = p;
                rs += p;
            }
        rs += __shfl_xor(rs, 16, 64);
        rs += __shfl_xor(rs, 32, 64);
        l_ += rs;

        // scatter P' -> per-wave frag LDS (bf16, values <= 2^8)
#pragma unroll
        for (int mt = 0; mt < 4; mt++)
#pragma unroll
            for (int h = 0; h < 2; h++) {
                u32 d = (u32)f2bf(sacc[mt][2 * h]) | ((u32)f2bf(sacc[mt][2 * h + 1]) << 16);
                int m = mt * 16 + quad * 4 + 2 * h;
                int frag = m >> 5;
                int kblk = (m >> 3) & 3;
                int j = (quad & 1) * 4 + 2 * h;
                *(u32*)&pw[frag * 512 + l15 * 32 + ((kblk ^ sw) * 8) + j] = d;
            }

        // O' += G^T(128ci x 64m) . P' — g frags straight from global (L2)
        const u16* gC = gB + ch * 64;
#pragma unroll
        for (int ks2 = 0; ks2 < 2; ks2++) {
            bf16x8 bfrag = *(const bf16x8*)&pw[ks2 * 512 + l15 * 32 + ((quad ^ sw) * 8)];
#pragma unroll
            for (int ct = 0; ct < 8; ct++) {
                bf16x8 a = *(const bf16x8*)&gC[(size_t)(ct * 16 + l15) * kM +
                                               ks2 * 32 + quad * 8];
                oacc[ct] = __builtin_amdgcn_mfma_f32_16x16x32_bf16(a, bfrag, oacc[ct], 0, 0, 0);
            }
        }
    }

    // epilogue: unnormalized O' (f32) + (m,l) per row; n = col = l15
    int n = n0 + w * 16 + l15;
    float* Ob = Opart + (((size_t)(sp * kB + b)) * kN + n) * kCI + quad * 4;
#pragma unroll
    for (int ct = 0; ct < 8; ct++)
        *(f32x4*)&Ob[ct * 16] = oacc[ct];
    if (quad == 0) {
        float2 mv;
        mv.x = m_;
        mv.y = l_;
        *(float2*)&ml[((size_t)(sp * kB + b) * kN + n) * 2] = mv;
    }
}

// ---------------------------------------------------------------------------
// MFMA final conv with fused split-combine:
// y[n][ci] = (O0*w0 + O1*w1) / (l0*w0 + l1*w1), then
// out[b][co][n] = Wws . y + bb[co] + v[b][co][n]   (fp32 out)
// ---------------------------------------------------------------------------
__global__ __launch_bounds__(256) void final_kernel(const float* __restrict__ Opart,
                                                    const float* __restrict__ ml,
                                                    const u16* __restrict__ Wws,
                                                    const float* __restrict__ bb,
                                                    const float* __restrict__ v,
                                                    float* __restrict__ out) {
    __shared__ __align__(16) u16 y_lds[64 * 136];
    int t = threadIdx.x, b = blockIdx.y, n0 = blockIdx.x * 64;
    int w = t >> 6, lane = t & 63, l15 = lane & 15, quad = lane >> 4;

    const float* O1 = Opart + (size_t)kB * kN * kCI;
#pragma unroll
    for (int i = 0; i < 4; i++) {
        int u = t + 256 * i, row = u >> 4, c8 = u & 15;
        int n = n0 + row;
        size_t mi = (size_t)b * kN + n;
        float2 ml0 = *(const float2*)&ml[mi * 2];
        float2 ml1 = *(const float2*)&ml[(mi + (size_t)kB * kN) * 2];
        float ms = fmaxf(ml0.x, ml1.x);
        float w0 = exp2f(ml0.x - ms), w1 = exp2f(ml1.x - ms);
        float inv = 1.0f / (ml0.y * w0 + ml1.y * w1);
        float a0 = w0 * inv, a1 = w1 * inv;
        size_t base = mi * kCI + c8 * 8;
        float4 x0 = *(const float4*)&Opart[base];
        float4 x0b = *(const float4*)&Opart[base + 4];
        float4 x1 = *(const float4*)&O1[base];
        float4 x1b = *(const float4*)&O1[base + 4];
        uint4 pk;
        pk.x = (u32)f2bf(x0.x * a0 + x1.x * a1) |
               ((u32)f2bf(x0.y * a0 + x1.y * a1) << 16);
        pk.y = (u32)f2bf(x0.z * a0 + x1.z * a1) |
               ((u32)f2bf(x0.w * a0 + x1.w * a1) << 16);
        pk.z = (u32)f2bf(x0b.x * a0 + x1b.x * a1) |
               ((u32)f2bf(x0b.y * a0 + x1b.y * a1) << 16);
        pk.w = (u32)f2bf(x0b.z * a0 + x1b.z * a1) |
               ((u32)f2bf(x0b.w * a0 + x1b.w * a1) << 16);
        *(uint4*)&y_lds[row * 136 + c8 * 8] = pk;
    }
    __syncthreads();

    bf16x8 af[4];
#pragma unroll
    for (int ks = 0; ks < 4; ks++)
        af[ks] = *(const bf16x8*)&y_lds[(w * 16 + l15) * 136 + ks * 32 + quad * 8];

#pragma unroll
    for (int ct = 0; ct < 16; ct++) {
        f32x4 a = (f32x4){0.f, 0.f, 0.f, 0.f};
#pragma unroll
        for (int ks = 0; ks < 4; ks++) {
            bf16x8 bf = *(const bf16x8*)&Wws[(ct * 16 + l15) * kCI + ks * 32 + quad * 8];
            a = __builtin_amdgcn_mfma_f32_16x16x32_bf16(af[ks], bf, a, 0, 0, 0);
        }
        int co = ct * 16 + l15;
        float bbv = bb[co];
        size_t base = (size_t)(b * kC + co) * kN + n0 + w * 16 + quad * 4;
        float4 vv = *(const float4*)&v[base];
        float4 ov;
        ov.x = a[0] + bbv + vv.x;
        ov.y = a[1] + bbv + vv.y;
        ov.z = a[2] + bbv + vv.z;
        ov.w = a[3] + bbv + vv.w;
        *(float4*)&out[base] = ov;
    }
}

// ---------------------------------------------------------------------------
extern "C" void kernel_launch(void* const* d_in, const int* in_sizes, int n_in,
                              void* d_out, int out_size, void* d_ws, size_t ws_size,
                              hipStream_t stream) {
    (void)in_sizes; (void)n_in; (void)out_size; (void)ws_size;
    const float* q     = (const float*)d_in[0];
    const float* k     = (const float*)d_in[1];
    const float* v     = (const float*)d_in[2];
    const float* Wg    = (const float*)d_in[3];
    const float* bg    = (const float*)d_in[4];
    const float* Wth   = (const float*)d_in[5];
    const float* bth   = (const float*)d_in[6];
    const float* Wph   = (const float*)d_in[7];
    const float* bph   = (const float*)d_in[8];
    const float* Ww    = (const float*)d_in[9];
    const float* bw    = (const float*)d_in[10];
    const float* gamma = (const float*)d_in[11];
    const float* beta  = (const float*)d_in[12];
    const float* mean  = (const float*)d_in[13];
    const float* var   = (const float*)d_in[14];
    float* out = (float*)d_out;

    u16* wsu = (u16*)d_ws;
    u16*   theta = wsu;                       // 4M u16 (8MB)
    u16*   phi   = theta + 4194304;           // 1M u16 (2MB)
    u16*   gbuf  = phi + 1048576;             // 1M u16 (2MB)
    u16*   Wthb  = gbuf + 1048576;
    u16*   Wphb  = Wthb + 32768;
    u16*   Wgb   = Wphb + 32768;
    u16*   Wwsb  = Wgb + 32768;
    float* bbuf  = (float*)(Wwsb + 32768);    // 256 f32
    float* bthl  = bbuf + 256;                // 128 f32
    float* mlb   = bthl + 128;                // 2*8*4096 float2 (512KB)
    float* Opart = mlb + 2 * kB * kN * 2;     // 2*8*4096*128 f32 (33.5MB)

    prep_kernel<<<dim3(512), 256, 0, stream>>>(Wth, bth, Wph, Wg, Ww, bw, gamma, beta,
                                               mean, var, Wthb, Wphb, Wgb, Wwsb,
                                               bbuf, bthl);
    convth_kernel<<<dim3(64, 8), 256, 0, stream>>>(k, Wthb, bthl, theta);
    convpg_kernel<<<dim3(16, 8, 2), 256, 0, stream>>>(q, v, Wphb, Wgb, bph, bg, phi, gbuf);
    attn_kernel<<<dim3(64, 8, 2), 256, 0, stream>>>(theta, phi, gbuf, Opart, mlb);
    final_kernel<<<dim3(64, 8), 256, 0, stream>>>(Opart, mlb, Wwsb, bbuf, v, out);
}